// Round 3
// baseline (5787.694 us; speedup 1.0000x reference)
//
#include <hip/hip_runtime.h>
#include <cstdio>

#define BB 4
#define TT 12
#define CC 64
#define NN 10000
#define HH 64
#define LL 2
#define NEDGE 2000
#define NNZT 80000
#define KTOP 10
#define DEMB 16
#define BT (BB*TT)
#define NCH 50
#define CHUNK 200
#define QPB 1024

typedef long long ll;

__device__ __forceinline__ float4 f4z() { return make_float4(0.f,0.f,0.f,0.f); }
__device__ __forceinline__ void f4add(float4& a, const float4 b){ a.x+=b.x; a.y+=b.y; a.z+=b.z; a.w+=b.w; }
__device__ __forceinline__ void f4fma(float4& a, float w, const float4 b){ a.x+=w*b.x; a.y+=w*b.y; a.z+=w*b.z; a.w+=w*b.w; }

// ---------------- graph setup ----------------
__global__ void deg_kernel(const int* __restrict__ nidx, const int* __restrict__ eidx,
                           int* __restrict__ ndeg, int* __restrict__ edeg) {
  int i = blockIdx.x*256 + threadIdx.x;
  if (i < NNZT) { atomicAdd(&ndeg[nidx[i]],1); atomicAdd(&edeg[eidx[i]],1); }
}

__global__ void exscan_kernel(const int* __restrict__ cnt, int* __restrict__ off, int n) {
  __shared__ int part[256];
  int tid = threadIdx.x;
  int chunk = (n + 255)/256;
  int lo = tid*chunk, hi = min(lo+chunk, n);
  int s = 0;
  for (int i=lo; i<hi; ++i) s += cnt[i];
  part[tid]=s; __syncthreads();
  if (tid==0){ int acc=0; for(int i=0;i<256;++i){int v=part[i];part[i]=acc;acc+=v;} off[n]=acc; }
  __syncthreads();
  int acc = part[tid];
  for (int i=lo; i<hi; ++i){ off[i]=acc; acc+=cnt[i]; }
}

__global__ void fill_csr_kernel(const int* __restrict__ nidx, const int* __restrict__ eidx,
                                const int* __restrict__ noff, const int* __restrict__ eoff,
                                int* __restrict__ ncur, int* __restrict__ ecur,
                                int* __restrict__ node_edges, int* __restrict__ edge_nodes) {
  int i = blockIdx.x*256 + threadIdx.x;
  if (i >= NNZT) return;
  int n = nidx[i], e = eidx[i];
  int pn = atomicAdd(&ncur[n],1);
  node_edges[noff[n]+pn] = e;
  int pe = atomicAdd(&ecur[e],1);
  edge_nodes[eoff[e]+pe] = n;
}

__global__ void invdeg_kernel(const int* __restrict__ ndeg, const int* __restrict__ edeg,
                              float* __restrict__ inv_n, float* __restrict__ inv_e) {
  int i = blockIdx.x*256+threadIdx.x;
  if (i < NN) inv_n[i] = 1.0f/fmaxf((float)ndeg[i],1.0f);
  if (i < NEDGE) inv_e[i] = 1.0f/fmaxf((float)edeg[i],1.0f);
}

// ---------------- top-k phase 1: per-chunk partial top-10, 4 queries/thread ----------------
__global__ void __launch_bounds__(256) topk1_kernel(const float* __restrict__ E,
                                                    float* __restrict__ pv, int* __restrict__ pi) {
  __shared__ float4 tile[CHUNK*4];   // 12.8 KB
  int tid = threadIdx.x;
  int qb = blockIdx.x;               // 0..9
  int ch = blockIdx.y;               // 0..NCH-1
  const float4* E4 = (const float4*)E;
  float4 q0[4], q1[4], q2[4], q3[4];
  #pragma unroll
  for (int u=0;u<4;++u) {
    int n = qb*QPB + u*256 + tid;
    int na = (n<NN)? n : 0;
    q0[u]=E4[(ll)na*4]; q1[u]=E4[(ll)na*4+1]; q2[u]=E4[(ll)na*4+2]; q3[u]=E4[(ll)na*4+3];
  }
  float tv[4][KTOP]; int ti[4][KTOP];
  #pragma unroll
  for (int u=0;u<4;++u)
    #pragma unroll
    for (int k=0;k<KTOP;++k){ tv[u][k]=-1.f; ti[u][k]=0x7fffffff; }
  int m0 = ch*CHUNK;
  for (int i=tid;i<CHUNK*4;i+=256) tile[i] = E4[(ll)m0*4 + i];
  __syncthreads();
  for (int mm=0;mm<CHUNK;++mm) {
    float4 a0=tile[mm*4],a1=tile[mm*4+1],a2=tile[mm*4+2],a3=tile[mm*4+3];
    int m = m0+mm;
    #pragma unroll
    for (int u=0;u<4;++u) {
      float dot = q0[u].x*a0.x+q0[u].y*a0.y+q0[u].z*a0.z+q0[u].w*a0.w
                + q1[u].x*a1.x+q1[u].y*a1.y+q1[u].z*a1.z+q1[u].w*a1.w
                + q2[u].x*a2.x+q2[u].y*a2.y+q2[u].z*a2.z+q2[u].w*a2.w
                + q3[u].x*a3.x+q3[u].y*a3.y+q3[u].z*a3.z+q3[u].w*a3.w;
      float s = fmaxf(dot, 0.f);
      if (s > tv[u][KTOP-1] || (s == tv[u][KTOP-1] && m < ti[u][KTOP-1])) {
        float cv=s; int ci=m;
        #pragma unroll
        for (int k=0;k<KTOP;++k){
          bool better=(cv>tv[u][k])||(cv==tv[u][k]&&ci<ti[u][k]);
          float nv=better?cv:tv[u][k]; int ni=better?ci:ti[u][k];
          float ov=better?tv[u][k]:cv; int oi=better?ti[u][k]:ci;
          tv[u][k]=nv; ti[u][k]=ni; cv=ov; ci=oi;
        }
      }
    }
  }
  #pragma unroll
  for (int u=0;u<4;++u) {
    int n = qb*QPB + u*256 + tid;
    if (n<NN) {
      #pragma unroll
      for (int k=0;k<KTOP;++k){
        pv[((ll)ch*NN+n)*KTOP+k]=tv[u][k];
        pi[((ll)ch*NN+n)*KTOP+k]=ti[u][k];
      }
    }
  }
}

// ---------------- top-k phase 2: 4-lane merge + softmax ----------------
__global__ void __launch_bounds__(64) topk2_kernel(const float* __restrict__ pv,
                                                   const int* __restrict__ pi,
                                                   int* __restrict__ tk_idx,
                                                   float* __restrict__ tk_w) {
  int tid = threadIdx.x;
  int sub = tid & 3;
  int n = blockIdx.x*16 + (tid>>2);   // 625*16 = 10000 exactly
  float tv[KTOP]; int ti[KTOP];
  #pragma unroll
  for (int k=0;k<KTOP;++k){ tv[k]=-1.f; ti[k]=0x7fffffff; }
  for (int ch=sub; ch<NCH; ch+=4) {
    const float* pvp = pv + ((ll)ch*NN+n)*KTOP;
    const int*  pip = pi + ((ll)ch*NN+n)*KTOP;
    for (int k=0;k<KTOP;++k) {
      float cv = pvp[k]; int ci = pip[k];
      if (!(cv>tv[KTOP-1] || (cv==tv[KTOP-1] && ci<ti[KTOP-1]))) break;  // sorted chunk
      #pragma unroll
      for (int q=0;q<KTOP;++q){
        bool better=(cv>tv[q])||(cv==tv[q]&&ci<ti[q]);
        float nv=better?cv:tv[q]; int ni=better?ci:ti[q];
        float ov=better?tv[q]:cv; int oi=better?ti[q]:ci;
        tv[q]=nv; ti[q]=ni; cv=ov; ci=oi;
      }
    }
  }
  float outv[KTOP]; int outi[KTOP];
  #pragma unroll
  for (int sel=0; sel<KTOP; ++sel) {
    float cv = tv[0]; int ci = ti[0]; int src = sub;
    #pragma unroll
    for (int ofs=1; ofs<4; ofs<<=1) {
      float ov = __shfl_xor(cv, ofs, 4);
      int oi = __shfl_xor(ci, ofs, 4);
      int os = __shfl_xor(src, ofs, 4);
      if (ov > cv || (ov == cv && (oi < ci || (oi == ci && os < src)))) { cv=ov; ci=oi; src=os; }
    }
    outv[sel]=cv; outi[sel]=ci;
    if (src == sub) {
      #pragma unroll
      for (int k=0;k<KTOP-1;++k){ tv[k]=tv[k+1]; ti[k]=ti[k+1]; }
      tv[KTOP-1]=-1.f; ti[KTOP-1]=0x7fffffff;
    }
  }
  if (sub == 0) {
    float mx = outv[0];
    float w[KTOP]; float sum=0.f;
    #pragma unroll
    for (int k=0;k<KTOP;++k){ w[k]=expf(outv[k]-mx); sum+=w[k]; }
    float inv = 1.f/sum;
    #pragma unroll
    for (int k=0;k<KTOP;++k){ tk_w[n*KTOP+k]=w[k]*inv; tk_idx[n*KTOP+k]=outi[k]; }
  }
}

// ---------------- (B,T,C,N) -> (B*T, N, C) transpose ----------------
__global__ void transpose_kernel(const float* __restrict__ src, float* __restrict__ dst) {
  __shared__ float tile[32][33];
  int bt = blockIdx.z;
  int n0 = blockIdx.x*32, c0 = blockIdx.y*32;
  for (int i=threadIdx.y; i<32; i+=8) {
    int c = c0+i, nn = n0+threadIdx.x;
    tile[i][threadIdx.x] = (nn<NN)? src[((ll)bt*CC + c)*NN + nn] : 0.0f;
  }
  __syncthreads();
  for (int i=threadIdx.y; i<32; i+=8) {
    int nn = n0+i, c = c0+threadIdx.x;
    if (nn<NN) dst[((ll)bt*NN+nn)*64 + c] = tile[threadIdx.x][i];
  }
}

// ---------------- edge aggregation (float4, shfl idx broadcast) ----------------
__global__ void __launch_bounds__(256) edge_agg_kernel(
    const float4* __restrict__ f4, float4* __restrict__ eagg4,
    const int* __restrict__ eoff, const int* __restrict__ enodes,
    const float* __restrict__ inv_e) {
  int tid = threadIdx.x;
  int e = blockIdx.x*16 + (tid>>4);
  int lane = tid & 15;
  int s = blockIdx.y;
  if (e >= NEDGE) return;
  int j0 = eoff[e], j1 = eoff[e+1];
  const float4* fb = f4 + (ll)s*NN*16;
  float4 acc = f4z();
  int j = j0;
  for (; j+16 <= j1; j += 16) {
    int idx = enodes[j+lane];
    #pragma unroll
    for (int jj=0; jj<16; ++jj) {
      int node = __shfl(idx, (tid & 48) + jj, 64);
      f4add(acc, fb[(ll)node*16 + lane]);
    }
  }
  for (; j<j1; ++j) {
    int node = enodes[j];
    f4add(acc, fb[(ll)node*16 + lane]);
  }
  float sc = inv_e[e];
  acc.x*=sc; acc.y*=sc; acc.z*=sc; acc.w*=sc;
  eagg4[((ll)s*NEDGE+e)*16+lane] = acc;
}

// ---------------- conv applied to x for all (b,t) (float4) ----------------
__global__ void __launch_bounds__(256) conv_x_kernel(
    const float4* __restrict__ xt4, const float4* __restrict__ eagg4,
    const int* __restrict__ noff, const int* __restrict__ nedges,
    const float* __restrict__ inv_n,
    const int* __restrict__ tk_idx, const float* __restrict__ tk_w,
    float4* __restrict__ cx4) {
  __shared__ int tki_s[16][KTOP];
  __shared__ float tkw_s[16][KTOP];
  int tid = threadIdx.x; int s = blockIdx.y; int n0 = blockIdx.x*16;
  for (int i=tid; i<16*KTOP; i+=256) {
    int r=i/KTOP, k=i%KTOP;
    tki_s[r][k] = tk_idx[(n0+r)*KTOP+k];
    tkw_s[r][k] = tk_w[(n0+r)*KTOP+k];
  }
  __syncthreads();
  int row = tid>>4, lane = tid&15;
  int n = n0 + row;
  float4 stv = f4z();
  int j0 = noff[n], j1 = noff[n+1];
  const float4* eb = eagg4 + (ll)s*NEDGE*16;
  for (int j=j0;j<j1;++j) f4add(stv, eb[(ll)nedges[j]*16 + lane]);
  float sc = 0.5f*inv_n[n];
  float4 adv = f4z();
  const float4* xb = xt4 + (ll)s*NN*16;
  #pragma unroll
  for (int k=0;k<KTOP;++k) f4fma(adv, tkw_s[row][k], xb[(ll)tki_s[row][k]*16 + lane]);
  float4 r;
  r.x = sc*stv.x + 0.5f*adv.x;
  r.y = sc*stv.y + 0.5f*adv.y;
  r.z = sc*stv.z + 0.5f*adv.z;
  r.w = sc*stv.w + 0.5f*adv.w;
  cx4[((ll)s*NN+n)*16+lane] = r;
}

// ---------------- GRU step kernel 1: gates z,r ----------------
__global__ void __launch_bounds__(256) step_zr_kernel(
    const float4* __restrict__ h4, const float4* __restrict__ cx4,
    const float4* __restrict__ eagg4,
    const float* __restrict__ Wz, const float* __restrict__ bz,
    const int* __restrict__ noff, const int* __restrict__ nedges,
    const float* __restrict__ inv_n,
    const int* __restrict__ tk_idx, const float* __restrict__ tk_w,
    const float* __restrict__ hs,
    float* __restrict__ rh, float* __restrict__ zout, int t, int hzero) {
  __shared__ __attribute__((aligned(16))) float in_t[32][136];
  __shared__ int tki_s[32][KTOP];
  __shared__ float tkw_s[32][KTOP];
  int tid = threadIdx.x;
  int b = blockIdx.y; int n0 = blockIdx.x*32;
  int bt = b*TT + t;
  for (int i=tid; i<32*KTOP; i+=256) {
    int r=i/KTOP, k=i%KTOP; int n=n0+r;
    tki_s[r][k] = (n<NN)? tk_idx[n*KTOP+k] : 0;
    tkw_s[r][k] = (n<NN)? tk_w[n*KTOP+k] : 0.f;
  }
  __syncthreads();
  #pragma unroll
  for (int kk=0;kk<2;++kk) {
    int slot = tid + kk*256;
    int row = slot>>4, lane = slot&15;
    int n = n0 + row;
    float4 cxv = f4z(), chv = f4z();
    if (n < NN) {
      cxv = cx4[((ll)bt*NN + n)*16 + lane];
      if (!hzero) {
        float4 stv = f4z();
        int j0 = noff[n], j1 = noff[n+1];
        const float4* eb = eagg4 + (ll)b*NEDGE*16;
        for (int j=j0;j<j1;++j) f4add(stv, eb[(ll)nedges[j]*16 + lane]);
        float sc = 0.5f*inv_n[n];
        float4 adv = f4z();
        const float4* hb = h4 + (ll)b*NN*16;
        #pragma unroll
        for (int k=0;k<KTOP;++k) f4fma(adv, tkw_s[row][k], hb[(ll)tki_s[row][k]*16 + lane]);
        chv.x = sc*stv.x + 0.5f*adv.x;
        chv.y = sc*stv.y + 0.5f*adv.y;
        chv.z = sc*stv.z + 0.5f*adv.z;
        chv.w = sc*stv.w + 0.5f*adv.w;
      }
    }
    *(float4*)&in_t[row][lane*4] = cxv;
    *(float4*)&in_t[row][64+lane*4] = chv;
  }
  __syncthreads();
  int col = tid & 127, rg = tid >> 7;
  float acc[16];
  float bias = bz[col];
  #pragma unroll
  for (int r=0;r<16;++r) acc[r]=bias;
  for (int i4=0;i4<32;++i4) {
    float w0 = Wz[(i4*4+0)*128+col];
    float w1 = Wz[(i4*4+1)*128+col];
    float w2 = Wz[(i4*4+2)*128+col];
    float w3 = Wz[(i4*4+3)*128+col];
    #pragma unroll
    for (int r=0;r<16;++r) {
      const float4 v = *(const float4*)&in_t[rg*16+r][i4*4];
      acc[r] += v.x*w0 + v.y*w1 + v.z*w2 + v.w*w3;
    }
  }
  #pragma unroll
  for (int r=0;r<16;++r) {
    int n = n0 + rg*16 + r;
    if (n < NN) {
      float v = 1.0f/(1.0f+expf(-acc[r]));
      if (col < 64) zout[((ll)b*NN+n)*64+col] = v;
      else {
        int c = col-64;
        float hv = hzero ? 0.f : hs[((ll)b*NN+n)*64+c];
        rh[((ll)b*NN+n)*64+c] = v*hv;
      }
    }
  }
}

// ---------------- GRU step kernel 2: candidate, h update, output ----------------
__global__ void __launch_bounds__(256) step_hy_kernel(
    const float4* __restrict__ rh4, const float4* __restrict__ cx4,
    const float4* __restrict__ eagg4,
    const float* __restrict__ Wc, const float* __restrict__ bc,
    const float* __restrict__ Wo, const float* __restrict__ bo,
    const int* __restrict__ noff, const int* __restrict__ nedges,
    const float* __restrict__ inv_n,
    const int* __restrict__ tk_idx, const float* __restrict__ tk_w,
    const float* __restrict__ zbuf, float* __restrict__ h,
    float* __restrict__ out, int t, int hzero) {
  __shared__ __attribute__((aligned(16))) float in2[32][136];
  __shared__ float hn[32][65];
  __shared__ __attribute__((aligned(16))) float yt[64][36];
  __shared__ int tki_s[32][KTOP];
  __shared__ float tkw_s[32][KTOP];
  int tid = threadIdx.x;
  int b = blockIdx.y; int n0 = blockIdx.x*32;
  int bt = b*TT + t;
  for (int i=tid; i<32*KTOP; i+=256) {
    int r=i/KTOP, k=i%KTOP; int n=n0+r;
    tki_s[r][k] = (n<NN)? tk_idx[n*KTOP+k] : 0;
    tkw_s[r][k] = (n<NN)? tk_w[n*KTOP+k] : 0.f;
  }
  __syncthreads();
  #pragma unroll
  for (int kk=0;kk<2;++kk) {
    int slot = tid + kk*256;
    int row = slot>>4, lane = slot&15;
    int n = n0 + row;
    float4 cxv = f4z(), chv = f4z();
    if (n < NN) {
      cxv = cx4[((ll)bt*NN + n)*16 + lane];
      if (!hzero) {
        float4 stv = f4z();
        int j0 = noff[n], j1 = noff[n+1];
        const float4* eb = eagg4 + (ll)b*NEDGE*16;
        for (int j=j0;j<j1;++j) f4add(stv, eb[(ll)nedges[j]*16 + lane]);
        float sc = 0.5f*inv_n[n];
        float4 adv = f4z();
        const float4* rb = rh4 + (ll)b*NN*16;
        #pragma unroll
        for (int k=0;k<KTOP;++k) f4fma(adv, tkw_s[row][k], rb[(ll)tki_s[row][k]*16 + lane]);
        chv.x = sc*stv.x + 0.5f*adv.x;
        chv.y = sc*stv.y + 0.5f*adv.y;
        chv.z = sc*stv.z + 0.5f*adv.z;
        chv.w = sc*stv.w + 0.5f*adv.w;
      }
    }
    *(float4*)&in2[row][lane*4] = cxv;
    *(float4*)&in2[row][64+lane*4] = chv;
  }
  __syncthreads();
  {
    int col = tid & 63, rg = tid >> 6;
    float acc[8];
    float bias = bc[col];
    #pragma unroll
    for (int r=0;r<8;++r) acc[r]=bias;
    for (int i4=0;i4<32;++i4) {
      float w0 = Wc[(i4*4+0)*64+col];
      float w1 = Wc[(i4*4+1)*64+col];
      float w2 = Wc[(i4*4+2)*64+col];
      float w3 = Wc[(i4*4+3)*64+col];
      #pragma unroll
      for (int r=0;r<8;++r) {
        const float4 v = *(const float4*)&in2[rg*8+r][i4*4];
        acc[r] += v.x*w0+v.y*w1+v.z*w2+v.w*w3;
      }
    }
    #pragma unroll
    for (int r=0;r<8;++r) {
      int row = rg*8+r; int n = n0+row;
      float hnew = 0.0f;
      if (n<NN) {
        float cval = tanhf(acc[r]);
        float z = zbuf[((ll)b*NN+n)*64+col];
        float hv = hzero ? 0.f : h[((ll)b*NN+n)*64+col];
        hnew = z*hv + (1.0f-z)*cval;
        h[((ll)b*NN+n)*64+col] = hnew;
      }
      hn[row][col] = hnew;
    }
  }
  __syncthreads();
  {
    int col = tid & 63, rg = tid >> 6;
    float acc[8];
    float bias = bo[col];
    #pragma unroll
    for (int r=0;r<8;++r) acc[r]=bias;
    for (int i4=0;i4<16;++i4) {
      float w0 = Wo[(i4*4+0)*64+col];
      float w1 = Wo[(i4*4+1)*64+col];
      float w2 = Wo[(i4*4+2)*64+col];
      float w3 = Wo[(i4*4+3)*64+col];
      #pragma unroll
      for (int r=0;r<8;++r) {
        float vx = hn[rg*8+r][i4*4+0];
        float vy = hn[rg*8+r][i4*4+1];
        float vz = hn[rg*8+r][i4*4+2];
        float vw = hn[rg*8+r][i4*4+3];
        acc[r] += vx*w0+vy*w1+vz*w2+vw*w3;
      }
    }
    #pragma unroll
    for (int r=0;r<8;++r) yt[col][rg*8+r] = acc[r];
  }
  __syncthreads();
  #pragma unroll
  for (int kk=0;kk<2;++kk) {
    int slot = tid + kk*256;
    int col = slot>>3, q = slot&7;
    int n = n0 + q*4;
    if (n < NN) {
      float4 y = *(const float4*)&yt[col][q*4];
      float4* dst = (float4*)&out[((ll)(b*TT+t)*64+col)*NN + n];
      float4 cur = *dst;
      cur.x += y.x; cur.y += y.y; cur.z += y.z; cur.w += y.w;
      *dst = cur;
    }
  }
}

extern "C" void kernel_launch(void* const* d_in, const int* in_sizes, int n_in,
                              void* d_out, int out_size, void* d_ws, size_t ws_size,
                              hipStream_t stream) {
  const float* x    = (const float*)d_in[0];
  const int*  hidx  = (const int*)d_in[1];
  const float* embs = (const float*)d_in[2];
  const float* W_zr = (const float*)d_in[3];
  const float* b_zr = (const float*)d_in[4];
  const float* W_c  = (const float*)d_in[5];
  const float* b_c  = (const float*)d_in[6];
  const float* W_out= (const float*)d_in[7];
  const float* b_out= (const float*)d_in[8];
  const int* node_idx = hidx;
  const int* edge_idx = hidx + NNZT;

  char* ws = (char*)d_ws;
  size_t off = 0;
  auto alloc = [&](size_t bytes) -> void* {
    void* p = ws + off; off += (bytes + 255) & ~(size_t)255; return p;
  };
  float* xt    = (float*)alloc((size_t)BT*NN*64*4);
  float* cx    = (float*)alloc((size_t)BT*NN*64*4);
  float* eaggx = (float*)alloc((size_t)BT*NEDGE*64*4);
  float* eaggh = (float*)alloc((size_t)BB*NEDGE*64*4);
  float* hbuf  = (float*)alloc((size_t)BB*NN*64*4);
  float* rhbuf = (float*)alloc((size_t)BB*NN*64*4);
  float* zbuf  = (float*)alloc((size_t)BB*NN*64*4);
  float* tkw   = (float*)alloc((size_t)NN*KTOP*4);
  float* inv_e = (float*)alloc(NEDGE*4);
  float* inv_n = (float*)alloc(NN*4);
  int* tki     = (int*)alloc((size_t)NN*KTOP*4);
  int* ndeg    = (int*)alloc(NN*4);
  int* edeg    = (int*)alloc(NEDGE*4);
  int* noff    = (int*)alloc((NN+1)*4);
  int* eoff    = (int*)alloc((NEDGE+1)*4);
  int* ncur    = (int*)alloc(NN*4);
  int* ecur    = (int*)alloc(NEDGE*4);
  int* nedges  = (int*)alloc(NNZT*4);
  int* enodes  = (int*)alloc(NNZT*4);
  if (off > ws_size) {
    fprintf(stderr, "kernel_launch: ws too small, need %zu have %zu\n", off, ws_size);
    return;
  }
  // topk partials alias cx (cx is written AFTER topk completes each layer)
  float* pv = cx;                                   // NCH*NN*KTOP = 5M floats
  int*   pi = (int*)(cx + (size_t)NCH*NN*KTOP);     // next 5M

  // out starts as x (residual base)
  hipMemcpyAsync(d_out, x, (size_t)BB*TT*CC*NN*4, hipMemcpyDeviceToDevice, stream);

  // graph structure (once)
  hipMemsetAsync(ndeg, 0, NN*4, stream);
  hipMemsetAsync(edeg, 0, NEDGE*4, stream);
  hipMemsetAsync(ncur, 0, NN*4, stream);
  hipMemsetAsync(ecur, 0, NEDGE*4, stream);
  deg_kernel<<<(NNZT+255)/256,256,0,stream>>>(node_idx, edge_idx, ndeg, edeg);
  exscan_kernel<<<1,256,0,stream>>>(ndeg, noff, NN);
  exscan_kernel<<<1,256,0,stream>>>(edeg, eoff, NEDGE);
  fill_csr_kernel<<<(NNZT+255)/256,256,0,stream>>>(node_idx, edge_idx, noff, eoff,
                                                   ncur, ecur, nedges, enodes);
  invdeg_kernel<<<(NN+255)/256,256,0,stream>>>(ndeg, edeg, inv_n, inv_e);

  float* outp = (float*)d_out;
  int nblk = (NN + 31)/32;  // 313
  for (int l=0; l<LL; ++l) {
    topk1_kernel<<<dim3(10, NCH),256,0,stream>>>(embs + (size_t)l*NN*DEMB, pv, pi);
    topk2_kernel<<<625,64,0,stream>>>(pv, pi, tki, tkw);
    transpose_kernel<<<dim3((NN+31)/32, CC/32, BT), dim3(32,8), 0, stream>>>(outp, xt);
    edge_agg_kernel<<<dim3((NEDGE+15)/16, BT),256,0,stream>>>(
        (const float4*)xt, (float4*)eaggx, eoff, enodes, inv_e);
    conv_x_kernel<<<dim3(NN/16, BT),256,0,stream>>>(
        (const float4*)xt, (const float4*)eaggx, noff, nedges, inv_n, tki, tkw, (float4*)cx);
    const float* Wz = W_zr + (size_t)l*128*128; const float* bz = b_zr + l*128;
    const float* Wc = W_c  + (size_t)l*128*64;  const float* bc = b_c + l*64;
    const float* Wo = W_out+ (size_t)l*64*64;   const float* bo = b_out + l*64;
    for (int t=0; t<TT; ++t) {
      int hz = (t==0) ? 1 : 0;
      if (!hz)
        edge_agg_kernel<<<dim3((NEDGE+15)/16, BB),256,0,stream>>>(
            (const float4*)hbuf, (float4*)eaggh, eoff, enodes, inv_e);
      step_zr_kernel<<<dim3(nblk, BB),256,0,stream>>>(
          (const float4*)hbuf, (const float4*)cx, (const float4*)eaggh, Wz, bz,
          noff, nedges, inv_n, tki, tkw, hbuf, rhbuf, zbuf, t, hz);
      if (!hz)
        edge_agg_kernel<<<dim3((NEDGE+15)/16, BB),256,0,stream>>>(
            (const float4*)rhbuf, (float4*)eaggh, eoff, enodes, inv_e);
      step_hy_kernel<<<dim3(nblk, BB),256,0,stream>>>(
          (const float4*)rhbuf, (const float4*)cx, (const float4*)eaggh, Wc, bc, Wo, bo,
          noff, nedges, inv_n, tki, tkw, zbuf, hbuf, outp, t, hz);
    }
  }
}

// Round 4
// 5082.405 us; speedup vs baseline: 1.1388x; 1.1388x over previous
//
#include <hip/hip_runtime.h>
#include <cstdio>

#define BB 4
#define TT 12
#define CC 64
#define NN 10000
#define HH 64
#define LL 2
#define NEDGE 2000
#define NNZT 80000
#define KTOP 10
#define DEMB 16
#define BT (BB*TT)
#define NTILE 40   // 40*256 = 10240 >= NN

typedef long long ll;
typedef unsigned long long u64;

__device__ __forceinline__ float4 f4z() { return make_float4(0.f,0.f,0.f,0.f); }
__device__ __forceinline__ void f4add(float4& a, const float4 b){ a.x+=b.x; a.y+=b.y; a.z+=b.z; a.w+=b.w; }
__device__ __forceinline__ void f4fma(float4& a, float w, const float4 b){ a.x+=w*b.x; a.y+=w*b.y; a.z+=w*b.z; a.w+=w*b.w; }

// ---------------- graph setup ----------------
__global__ void deg_kernel(const int* __restrict__ nidx, const int* __restrict__ eidx,
                           int* __restrict__ ndeg, int* __restrict__ edeg) {
  int i = blockIdx.x*256 + threadIdx.x;
  if (i < NNZT) { atomicAdd(&ndeg[nidx[i]],1); atomicAdd(&edeg[eidx[i]],1); }
}

__global__ void exscan_kernel(const int* __restrict__ cnt, int* __restrict__ off, int n) {
  __shared__ int part[256];
  int tid = threadIdx.x;
  int chunk = (n + 255)/256;
  int lo = tid*chunk, hi = min(lo+chunk, n);
  int s = 0;
  for (int i=lo; i<hi; ++i) s += cnt[i];
  part[tid]=s; __syncthreads();
  if (tid==0){ int acc=0; for(int i=0;i<256;++i){int v=part[i];part[i]=acc;acc+=v;} off[n]=acc; }
  __syncthreads();
  int acc = part[tid];
  for (int i=lo; i<hi; ++i){ off[i]=acc; acc+=cnt[i]; }
}

__global__ void fill_csr_kernel(const int* __restrict__ nidx, const int* __restrict__ eidx,
                                const int* __restrict__ noff, const int* __restrict__ eoff,
                                int* __restrict__ ncur, int* __restrict__ ecur,
                                int* __restrict__ node_edges, int* __restrict__ edge_nodes) {
  int i = blockIdx.x*256 + threadIdx.x;
  if (i >= NNZT) return;
  int n = nidx[i], e = eidx[i];
  int pn = atomicAdd(&ncur[n],1);
  node_edges[noff[n]+pn] = e;
  int pe = atomicAdd(&ecur[e],1);
  edge_nodes[eoff[e]+pe] = n;
}

__global__ void invdeg_kernel(const int* __restrict__ ndeg, const int* __restrict__ edeg,
                              float* __restrict__ inv_n, float* __restrict__ inv_e) {
  int i = blockIdx.x*256+threadIdx.x;
  if (i < NN) inv_n[i] = 1.0f/fmaxf((float)ndeg[i],1.0f);
  if (i < NEDGE) inv_e[i] = 1.0f/fmaxf((float)edeg[i],1.0f);
}

// ---------------- top-k: wave-uniform threshold + buffered bitonic reselect ----------------
__device__ __forceinline__ u64 sortstep(u64 X, int j, bool dir, int lane) {
  u64 p = __shfl_xor(X, j);
  bool lower = ((lane & j) == 0);
  bool keep_min = (dir == lower);
  bool xlt = (X < p);
  u64 mn = xlt ? X : p;
  u64 mx = xlt ? p : X;
  return keep_min ? mn : mx;
}

// sort (top-10 slots [0..9] + cnt appended at [10..)) -> new top-10 in [0..9], thr, cnt=0
__device__ __forceinline__ void reselect(u64* bq, u64& thr, int& cnt, int lane) {
  int tot = 10 + cnt;                       // <= 113 < 128
  u64 A = (lane < tot)      ? bq[lane]      : 0ull;   // pos = lane
  u64 B = (lane + 64 < tot) ? bq[lane + 64] : 0ull;   // pos = lane+64
  // bitonic ascending sort of 128
  for (int k = 2; k <= 32; k <<= 1) {
    for (int j = k >> 1; j >= 1; j >>= 1) {
      bool dir = ((lane & k) == 0);
      A = sortstep(A, j, dir, lane);
      B = sortstep(B, j, dir, lane);
    }
  }
  for (int j = 32; j >= 1; j >>= 1) {       // k = 64
    A = sortstep(A, j, true,  lane);        // pos<64  -> ascending
    B = sortstep(B, j, false, lane);        // pos>=64 -> descending
  }
  { // k = 128, j = 64: local exchange (partner is other register, asc)
    bool lt = (A < B);
    u64 mn = lt ? A : B, mx = lt ? B : A;
    A = mn; B = mx;
  }
  for (int j = 32; j >= 1; j >>= 1) {       // k = 128 tail
    A = sortstep(A, j, true, lane);
    B = sortstep(B, j, true, lane);
  }
  // ascending: rank t (0=max) at pos 127-t -> B of lane 63-t
  if (lane >= 54) bq[63 - lane] = B;        // slots 0..9 descending
  thr = __shfl(B, 54);                      // pos 118 = rank 9
  cnt = 0;
}

__global__ void __launch_bounds__(256) topk_kernel(const float* __restrict__ E,
                                                   int* __restrict__ tk_idx,
                                                   float* __restrict__ tk_w) {
  __shared__ float4 tile[4*256];            // [j][c] transposed, 16 KB
  __shared__ u64 buf[16][128];              // 16 KB, per-query hit buffer
  int tid = threadIdx.x;
  int wv = tid >> 6, lane = tid & 63;
  int qbase = blockIdx.x*16 + wv*4;         // 625*16 = 10000 exactly
  const float4* E4 = (const float4*)E;
  float4 q[4][4];
  #pragma unroll
  for (int u=0;u<4;++u) {
    int n = qbase + u;
    #pragma unroll
    for (int j=0;j<4;++j) q[u][j] = E4[(ll)n*4 + j];
  }
  u64 thr[4] = {0,0,0,0};
  int cnt[4] = {0,0,0,0};
  if (tid < 256) {                          // init top-10 slots to 0
    buf[tid>>4][tid&15] = 0ull;
  }
  for (int tb=0; tb<NTILE; ++tb) {
    int cbase = tb*256;
    __syncthreads();
    #pragma unroll
    for (int k=0;k<4;++k) {
      int idx = tid + k*256;                // 0..1023
      int c = cbase + (idx>>2);
      float4 v = (c < NN) ? E4[(ll)c*4 + (idx&3)] : f4z();
      tile[(idx&3)*256 + (idx>>2)] = v;
    }
    __syncthreads();
    for (int r=0;r<4;++r) {
      int cl = r*64 + lane;
      int cand = cbase + cl;
      float4 a0 = tile[cl], a1 = tile[256+cl], a2 = tile[512+cl], a3 = tile[768+cl];
      u64 low = (u64)(0x00FFFFFFu - (unsigned)cand);
      bool valid = (cand < NN);
      u64 key[4];
      #pragma unroll
      for (int u=0;u<4;++u) {
        float dot = q[u][0].x*a0.x + q[u][0].y*a0.y + q[u][0].z*a0.z + q[u][0].w*a0.w
                  + q[u][1].x*a1.x + q[u][1].y*a1.y + q[u][1].z*a1.z + q[u][1].w*a1.w
                  + q[u][2].x*a2.x + q[u][2].y*a2.y + q[u][2].z*a2.z + q[u][2].w*a2.w
                  + q[u][3].x*a3.x + q[u][3].y*a3.y + q[u][3].z*a3.z + q[u][3].w*a3.w;
        float s = fmaxf(dot, 0.f);
        u64 kk = ((u64)__float_as_uint(s) << 32) | low;
        key[u] = valid ? kk : 0ull;
      }
      #pragma unroll
      for (int u=0;u<4;++u) {
        u64 mask = __ballot(key[u] > thr[u]);
        if (mask) {                                   // wave-uniform
          if (key[u] > thr[u]) {
            int myofs = (int)__popcll(mask & ((1ull<<lane)-1ull));
            buf[wv*4+u][10 + cnt[u] + myofs] = key[u];
          }
          cnt[u] += (int)__popcll(mask);
          if (cnt[u] >= 40) reselect(&buf[wv*4+u][0], thr[u], cnt[u], lane);
        }
      }
    }
  }
  // finalize + softmax
  #pragma unroll
  for (int u=0;u<4;++u) {
    u64* bq = &buf[wv*4+u][0];
    if (cnt[u] > 0) reselect(bq, thr[u], cnt[u], lane);
    u64 k10 = (lane < 10) ? bq[lane] : 0ull;
    float v = __uint_as_float((unsigned)(k10 >> 32));
    int idx = 0x00FFFFFF - (int)(k10 & 0xFFFFFFFFull);
    float v0 = __shfl(v, 0);
    float e = (lane < 10) ? expf(v - v0) : 0.f;
    float s = e;
    for (int o=1;o<16;o<<=1) s += __shfl_xor(s, o);
    if (lane < 10) {
      int n = qbase + u;
      tk_w[n*KTOP + lane] = e / s;
      tk_idx[n*KTOP + lane] = idx;
    }
  }
}

// ---------------- (B,T,C,N) -> (B*T, N, C) transpose ----------------
__global__ void transpose_kernel(const float* __restrict__ src, float* __restrict__ dst) {
  __shared__ float tile[32][33];
  int bt = blockIdx.z;
  int n0 = blockIdx.x*32, c0 = blockIdx.y*32;
  for (int i=threadIdx.y; i<32; i+=8) {
    int c = c0+i, nn = n0+threadIdx.x;
    tile[i][threadIdx.x] = (nn<NN)? src[((ll)bt*CC + c)*NN + nn] : 0.0f;
  }
  __syncthreads();
  for (int i=threadIdx.y; i<32; i+=8) {
    int nn = n0+i, c = c0+threadIdx.x;
    if (nn<NN) dst[((ll)bt*NN+nn)*64 + c] = tile[threadIdx.x][i];
  }
}

// ---------------- edge aggregation (float4, shfl idx broadcast) ----------------
__global__ void __launch_bounds__(256) edge_agg_kernel(
    const float4* __restrict__ f4, float4* __restrict__ eagg4,
    const int* __restrict__ eoff, const int* __restrict__ enodes,
    const float* __restrict__ inv_e) {
  int tid = threadIdx.x;
  int e = blockIdx.x*16 + (tid>>4);
  int lane = tid & 15;
  int s = blockIdx.y;
  if (e >= NEDGE) return;
  int j0 = eoff[e], j1 = eoff[e+1];
  const float4* fb = f4 + (ll)s*NN*16;
  float4 acc = f4z();
  int j = j0;
  for (; j+16 <= j1; j += 16) {
    int idx = enodes[j+lane];
    #pragma unroll
    for (int jj=0; jj<16; ++jj) {
      int node = __shfl(idx, (tid & 48) + jj, 64);
      f4add(acc, fb[(ll)node*16 + lane]);
    }
  }
  for (; j<j1; ++j) {
    int node = enodes[j];
    f4add(acc, fb[(ll)node*16 + lane]);
  }
  float sc = inv_e[e];
  acc.x*=sc; acc.y*=sc; acc.z*=sc; acc.w*=sc;
  eagg4[((ll)s*NEDGE+e)*16+lane] = acc;
}

// ---------------- conv applied to x for all (b,t) (float4) ----------------
__global__ void __launch_bounds__(256) conv_x_kernel(
    const float4* __restrict__ xt4, const float4* __restrict__ eagg4,
    const int* __restrict__ noff, const int* __restrict__ nedges,
    const float* __restrict__ inv_n,
    const int* __restrict__ tk_idx, const float* __restrict__ tk_w,
    float4* __restrict__ cx4) {
  __shared__ int tki_s[16][KTOP];
  __shared__ float tkw_s[16][KTOP];
  int tid = threadIdx.x; int s = blockIdx.y; int n0 = blockIdx.x*16;
  for (int i=tid; i<16*KTOP; i+=256) {
    int r=i/KTOP, k=i%KTOP;
    tki_s[r][k] = tk_idx[(n0+r)*KTOP+k];
    tkw_s[r][k] = tk_w[(n0+r)*KTOP+k];
  }
  __syncthreads();
  int row = tid>>4, lane = tid&15;
  int n = n0 + row;
  float4 stv = f4z();
  int j0 = noff[n], j1 = noff[n+1];
  const float4* eb = eagg4 + (ll)s*NEDGE*16;
  for (int j=j0;j<j1;++j) f4add(stv, eb[(ll)nedges[j]*16 + lane]);
  float sc = 0.5f*inv_n[n];
  float4 adv = f4z();
  const float4* xb = xt4 + (ll)s*NN*16;
  #pragma unroll
  for (int k=0;k<KTOP;++k) f4fma(adv, tkw_s[row][k], xb[(ll)tki_s[row][k]*16 + lane]);
  float4 r;
  r.x = sc*stv.x + 0.5f*adv.x;
  r.y = sc*stv.y + 0.5f*adv.y;
  r.z = sc*stv.z + 0.5f*adv.z;
  r.w = sc*stv.w + 0.5f*adv.w;
  cx4[((ll)s*NN+n)*16+lane] = r;
}

// ---------------- GRU step kernel 1: gates z,r ----------------
__global__ void __launch_bounds__(256) step_zr_kernel(
    const float4* __restrict__ h4, const float4* __restrict__ cx4,
    const float4* __restrict__ eagg4,
    const float* __restrict__ Wz, const float* __restrict__ bz,
    const int* __restrict__ noff, const int* __restrict__ nedges,
    const float* __restrict__ inv_n,
    const int* __restrict__ tk_idx, const float* __restrict__ tk_w,
    const float* __restrict__ hs,
    float* __restrict__ rh, float* __restrict__ zout, int t, int hzero) {
  __shared__ __attribute__((aligned(16))) float in_t[32][136];
  __shared__ int tki_s[32][KTOP];
  __shared__ float tkw_s[32][KTOP];
  int tid = threadIdx.x;
  int b = blockIdx.y; int n0 = blockIdx.x*32;
  int bt = b*TT + t;
  for (int i=tid; i<32*KTOP; i+=256) {
    int r=i/KTOP, k=i%KTOP; int n=n0+r;
    tki_s[r][k] = (n<NN)? tk_idx[n*KTOP+k] : 0;
    tkw_s[r][k] = (n<NN)? tk_w[n*KTOP+k] : 0.f;
  }
  __syncthreads();
  #pragma unroll
  for (int kk=0;kk<2;++kk) {
    int slot = tid + kk*256;
    int row = slot>>4, lane = slot&15;
    int n = n0 + row;
    float4 cxv = f4z(), chv = f4z();
    if (n < NN) {
      cxv = cx4[((ll)bt*NN + n)*16 + lane];
      if (!hzero) {
        float4 stv = f4z();
        int j0 = noff[n], j1 = noff[n+1];
        const float4* eb = eagg4 + (ll)b*NEDGE*16;
        for (int j=j0;j<j1;++j) f4add(stv, eb[(ll)nedges[j]*16 + lane]);
        float sc = 0.5f*inv_n[n];
        float4 adv = f4z();
        const float4* hb = h4 + (ll)b*NN*16;
        #pragma unroll
        for (int k=0;k<KTOP;++k) f4fma(adv, tkw_s[row][k], hb[(ll)tki_s[row][k]*16 + lane]);
        chv.x = sc*stv.x + 0.5f*adv.x;
        chv.y = sc*stv.y + 0.5f*adv.y;
        chv.z = sc*stv.z + 0.5f*adv.z;
        chv.w = sc*stv.w + 0.5f*adv.w;
      }
    }
    *(float4*)&in_t[row][lane*4] = cxv;
    *(float4*)&in_t[row][64+lane*4] = chv;
  }
  __syncthreads();
  int col = tid & 127, rg = tid >> 7;
  float acc[16];
  float bias = bz[col];
  #pragma unroll
  for (int r=0;r<16;++r) acc[r]=bias;
  for (int i4=0;i4<32;++i4) {
    float w0 = Wz[(i4*4+0)*128+col];
    float w1 = Wz[(i4*4+1)*128+col];
    float w2 = Wz[(i4*4+2)*128+col];
    float w3 = Wz[(i4*4+3)*128+col];
    #pragma unroll
    for (int r=0;r<16;++r) {
      const float4 v = *(const float4*)&in_t[rg*16+r][i4*4];
      acc[r] += v.x*w0 + v.y*w1 + v.z*w2 + v.w*w3;
    }
  }
  #pragma unroll
  for (int r=0;r<16;++r) {
    int n = n0 + rg*16 + r;
    if (n < NN) {
      float v = 1.0f/(1.0f+expf(-acc[r]));
      if (col < 64) zout[((ll)b*NN+n)*64+col] = v;
      else {
        int c = col-64;
        float hv = hzero ? 0.f : hs[((ll)b*NN+n)*64+c];
        rh[((ll)b*NN+n)*64+c] = v*hv;
      }
    }
  }
}

// ---------------- GRU step kernel 2: candidate, h update, output ----------------
__global__ void __launch_bounds__(256) step_hy_kernel(
    const float4* __restrict__ rh4, const float4* __restrict__ cx4,
    const float4* __restrict__ eagg4,
    const float* __restrict__ Wc, const float* __restrict__ bc,
    const float* __restrict__ Wo, const float* __restrict__ bo,
    const int* __restrict__ noff, const int* __restrict__ nedges,
    const float* __restrict__ inv_n,
    const int* __restrict__ tk_idx, const float* __restrict__ tk_w,
    const float* __restrict__ zbuf, float* __restrict__ h,
    float* __restrict__ out, int t, int hzero) {
  __shared__ __attribute__((aligned(16))) float in2[32][136];
  __shared__ float hn[32][65];
  __shared__ __attribute__((aligned(16))) float yt[64][36];
  __shared__ int tki_s[32][KTOP];
  __shared__ float tkw_s[32][KTOP];
  int tid = threadIdx.x;
  int b = blockIdx.y; int n0 = blockIdx.x*32;
  int bt = b*TT + t;
  for (int i=tid; i<32*KTOP; i+=256) {
    int r=i/KTOP, k=i%KTOP; int n=n0+r;
    tki_s[r][k] = (n<NN)? tk_idx[n*KTOP+k] : 0;
    tkw_s[r][k] = (n<NN)? tk_w[n*KTOP+k] : 0.f;
  }
  __syncthreads();
  #pragma unroll
  for (int kk=0;kk<2;++kk) {
    int slot = tid + kk*256;
    int row = slot>>4, lane = slot&15;
    int n = n0 + row;
    float4 cxv = f4z(), chv = f4z();
    if (n < NN) {
      cxv = cx4[((ll)bt*NN + n)*16 + lane];
      if (!hzero) {
        float4 stv = f4z();
        int j0 = noff[n], j1 = noff[n+1];
        const float4* eb = eagg4 + (ll)b*NEDGE*16;
        for (int j=j0;j<j1;++j) f4add(stv, eb[(ll)nedges[j]*16 + lane]);
        float sc = 0.5f*inv_n[n];
        float4 adv = f4z();
        const float4* rb = rh4 + (ll)b*NN*16;
        #pragma unroll
        for (int k=0;k<KTOP;++k) f4fma(adv, tkw_s[row][k], rb[(ll)tki_s[row][k]*16 + lane]);
        chv.x = sc*stv.x + 0.5f*adv.x;
        chv.y = sc*stv.y + 0.5f*adv.y;
        chv.z = sc*stv.z + 0.5f*adv.z;
        chv.w = sc*stv.w + 0.5f*adv.w;
      }
    }
    *(float4*)&in2[row][lane*4] = cxv;
    *(float4*)&in2[row][64+lane*4] = chv;
  }
  __syncthreads();
  {
    int col = tid & 63, rg = tid >> 6;
    float acc[8];
    float bias = bc[col];
    #pragma unroll
    for (int r=0;r<8;++r) acc[r]=bias;
    for (int i4=0;i4<32;++i4) {
      float w0 = Wc[(i4*4+0)*64+col];
      float w1 = Wc[(i4*4+1)*64+col];
      float w2 = Wc[(i4*4+2)*64+col];
      float w3 = Wc[(i4*4+3)*64+col];
      #pragma unroll
      for (int r=0;r<8;++r) {
        const float4 v = *(const float4*)&in2[rg*8+r][i4*4];
        acc[r] += v.x*w0+v.y*w1+v.z*w2+v.w*w3;
      }
    }
    #pragma unroll
    for (int r=0;r<8;++r) {
      int row = rg*8+r; int n = n0+row;
      float hnew = 0.0f;
      if (n<NN) {
        float cval = tanhf(acc[r]);
        float z = zbuf[((ll)b*NN+n)*64+col];
        float hv = hzero ? 0.f : h[((ll)b*NN+n)*64+col];
        hnew = z*hv + (1.0f-z)*cval;
        h[((ll)b*NN+n)*64+col] = hnew;
      }
      hn[row][col] = hnew;
    }
  }
  __syncthreads();
  {
    int col = tid & 63, rg = tid >> 6;
    float acc[8];
    float bias = bo[col];
    #pragma unroll
    for (int r=0;r<8;++r) acc[r]=bias;
    for (int i4=0;i4<16;++i4) {
      float w0 = Wo[(i4*4+0)*64+col];
      float w1 = Wo[(i4*4+1)*64+col];
      float w2 = Wo[(i4*4+2)*64+col];
      float w3 = Wo[(i4*4+3)*64+col];
      #pragma unroll
      for (int r=0;r<8;++r) {
        float vx = hn[rg*8+r][i4*4+0];
        float vy = hn[rg*8+r][i4*4+1];
        float vz = hn[rg*8+r][i4*4+2];
        float vw = hn[rg*8+r][i4*4+3];
        acc[r] += vx*w0+vy*w1+vz*w2+vw*w3;
      }
    }
    #pragma unroll
    for (int r=0;r<8;++r) yt[col][rg*8+r] = acc[r];
  }
  __syncthreads();
  #pragma unroll
  for (int kk=0;kk<2;++kk) {
    int slot = tid + kk*256;
    int col = slot>>3, q = slot&7;
    int n = n0 + q*4;
    if (n < NN) {
      float4 y = *(const float4*)&yt[col][q*4];
      float4* dst = (float4*)&out[((ll)(b*TT+t)*64+col)*NN + n];
      float4 cur = *dst;
      cur.x += y.x; cur.y += y.y; cur.z += y.z; cur.w += y.w;
      *dst = cur;
    }
  }
}

extern "C" void kernel_launch(void* const* d_in, const int* in_sizes, int n_in,
                              void* d_out, int out_size, void* d_ws, size_t ws_size,
                              hipStream_t stream) {
  const float* x    = (const float*)d_in[0];
  const int*  hidx  = (const int*)d_in[1];
  const float* embs = (const float*)d_in[2];
  const float* W_zr = (const float*)d_in[3];
  const float* b_zr = (const float*)d_in[4];
  const float* W_c  = (const float*)d_in[5];
  const float* b_c  = (const float*)d_in[6];
  const float* W_out= (const float*)d_in[7];
  const float* b_out= (const float*)d_in[8];
  const int* node_idx = hidx;
  const int* edge_idx = hidx + NNZT;

  char* ws = (char*)d_ws;
  size_t off = 0;
  auto alloc = [&](size_t bytes) -> void* {
    void* p = ws + off; off += (bytes + 255) & ~(size_t)255; return p;
  };
  float* xt    = (float*)alloc((size_t)BT*NN*64*4);
  float* cx    = (float*)alloc((size_t)BT*NN*64*4);
  float* eaggx = (float*)alloc((size_t)BT*NEDGE*64*4);
  float* eaggh = (float*)alloc((size_t)BB*NEDGE*64*4);
  float* hbuf  = (float*)alloc((size_t)BB*NN*64*4);
  float* rhbuf = (float*)alloc((size_t)BB*NN*64*4);
  float* zbuf  = (float*)alloc((size_t)BB*NN*64*4);
  float* tkw   = (float*)alloc((size_t)NN*KTOP*4);
  float* inv_e = (float*)alloc(NEDGE*4);
  float* inv_n = (float*)alloc(NN*4);
  int* tki     = (int*)alloc((size_t)NN*KTOP*4);
  int* ndeg    = (int*)alloc(NN*4);
  int* edeg    = (int*)alloc(NEDGE*4);
  int* noff    = (int*)alloc((NN+1)*4);
  int* eoff    = (int*)alloc((NEDGE+1)*4);
  int* ncur    = (int*)alloc(NN*4);
  int* ecur    = (int*)alloc(NEDGE*4);
  int* nedges  = (int*)alloc(NNZT*4);
  int* enodes  = (int*)alloc(NNZT*4);
  if (off > ws_size) {
    fprintf(stderr, "kernel_launch: ws too small, need %zu have %zu\n", off, ws_size);
    return;
  }

  // out starts as x (residual base)
  hipMemcpyAsync(d_out, x, (size_t)BB*TT*CC*NN*4, hipMemcpyDeviceToDevice, stream);

  // graph structure (once)
  hipMemsetAsync(ndeg, 0, NN*4, stream);
  hipMemsetAsync(edeg, 0, NEDGE*4, stream);
  hipMemsetAsync(ncur, 0, NN*4, stream);
  hipMemsetAsync(ecur, 0, NEDGE*4, stream);
  deg_kernel<<<(NNZT+255)/256,256,0,stream>>>(node_idx, edge_idx, ndeg, edeg);
  exscan_kernel<<<1,256,0,stream>>>(ndeg, noff, NN);
  exscan_kernel<<<1,256,0,stream>>>(edeg, eoff, NEDGE);
  fill_csr_kernel<<<(NNZT+255)/256,256,0,stream>>>(node_idx, edge_idx, noff, eoff,
                                                   ncur, ecur, nedges, enodes);
  invdeg_kernel<<<(NN+255)/256,256,0,stream>>>(ndeg, edeg, inv_n, inv_e);

  float* outp = (float*)d_out;
  int nblk = (NN + 31)/32;  // 313
  for (int l=0; l<LL; ++l) {
    topk_kernel<<<625,256,0,stream>>>(embs + (size_t)l*NN*DEMB, tki, tkw);
    transpose_kernel<<<dim3((NN+31)/32, CC/32, BT), dim3(32,8), 0, stream>>>(outp, xt);
    edge_agg_kernel<<<dim3((NEDGE+15)/16, BT),256,0,stream>>>(
        (const float4*)xt, (float4*)eaggx, eoff, enodes, inv_e);
    conv_x_kernel<<<dim3(NN/16, BT),256,0,stream>>>(
        (const float4*)xt, (const float4*)eaggx, noff, nedges, inv_n, tki, tkw, (float4*)cx);
    const float* Wz = W_zr + (size_t)l*128*128; const float* bz = b_zr + l*128;
    const float* Wc = W_c  + (size_t)l*128*64;  const float* bc = b_c + l*64;
    const float* Wo = W_out+ (size_t)l*64*64;   const float* bo = b_out + l*64;
    for (int t=0; t<TT; ++t) {
      int hz = (t==0) ? 1 : 0;
      if (!hz)
        edge_agg_kernel<<<dim3((NEDGE+15)/16, BB),256,0,stream>>>(
            (const float4*)hbuf, (float4*)eaggh, eoff, enodes, inv_e);
      step_zr_kernel<<<dim3(nblk, BB),256,0,stream>>>(
          (const float4*)hbuf, (const float4*)cx, (const float4*)eaggh, Wz, bz,
          noff, nedges, inv_n, tki, tkw, hbuf, rhbuf, zbuf, t, hz);
      if (!hz)
        edge_agg_kernel<<<dim3((NEDGE+15)/16, BB),256,0,stream>>>(
            (const float4*)rhbuf, (float4*)eaggh, eoff, enodes, inv_e);
      step_hy_kernel<<<dim3(nblk, BB),256,0,stream>>>(
          (const float4*)rhbuf, (const float4*)cx, (const float4*)eaggh, Wc, bc, Wo, bo,
          noff, nedges, inv_n, tki, tkw, zbuf, hbuf, outp, t, hz);
    }
  }
}